// Round 11
// baseline (222.742 us; speedup 1.0000x reference)
//
#include <hip/hip_runtime.h>
#include <hip/hip_bf16.h>

typedef __bf16 bf16;
typedef __attribute__((ext_vector_type(8))) __bf16 bf16x8;
typedef __attribute__((ext_vector_type(4))) __bf16 bf16x4;
typedef __attribute__((ext_vector_type(4))) float f32x4;

#define NEGV (-1e18f)
#define LOG2E 1.4426950408889634f

__device__ __forceinline__ bf16 f2b(float f) {
    unsigned u = __builtin_bit_cast(unsigned, f);
    u += 0x7fffu + ((u >> 16) & 1u);
    unsigned short h = (unsigned short)(u >> 16);
    return __builtin_bit_cast(bf16, h);
}

__device__ __forceinline__ f32x4 mfma16(bf16x8 a, bf16x8 b, f32x4 c) {
    return __builtin_amdgcn_mfma_f32_16x16x32_bf16(a, b, c, 0, 0, 0);
}

__device__ __forceinline__ void gl16(const void* g, void* l) {
    __builtin_amdgcn_global_load_lds((const __attribute__((address_space(1))) void*)g,
                                     (__attribute__((address_space(3))) void*)l, 16, 0, 0);
}

// ---------------------------------------------------------------------------
// prep: weight transpose + f32->bf16 only (activations now fused into gemm8).
// grid 1024 = 4 weights x 256 tiles.
// ---------------------------------------------------------------------------
__global__ __launch_bounds__(256) void prep(const float* __restrict__ W0,
                                            const float* __restrict__ W1,
                                            const float* __restrict__ W2,
                                            const float* __restrict__ W3,
                                            bf16* __restrict__ Wout) {
    __shared__ float tile[64][65];
    int w = blockIdx.x;
    int t = threadIdx.x;
    int z = w >> 8;
    const float* Ws[4] = {W0, W1, W2, W3};
    const float* W = Ws[z];
    bf16* O = Wout + ((size_t)z << 20);
    int k0 = (w & 15) * 64, n0 = ((w >> 4) & 15) * 64;
#pragma unroll
    for (int p = 0; p < 4; p++) {
        int r = (t >> 4) + p * 16, c = (t & 15) * 4;
        float4 v = *(const float4*)&W[(size_t)(k0 + r) * 1024 + n0 + c];
        tile[r][c] = v.x; tile[r][c + 1] = v.y; tile[r][c + 2] = v.z; tile[r][c + 3] = v.w;
    }
    __syncthreads();
#pragma unroll
    for (int p = 0; p < 4; p++) {
        int r = (t >> 4) + p * 16, c = (t & 15) * 4;
        bf16x4 o;
        o[0] = f2b(tile[c][r]); o[1] = f2b(tile[c + 1][r]);
        o[2] = f2b(tile[c + 2][r]); o[3] = f2b(tile[c + 3][r]);
        *(bf16x4*)&O[(size_t)(n0 + r) * 1024 + k0 + c] = o;
    }
}

// ---------------------------------------------------------------------------
// 4-phase 256x256 GEMM with FUSED f32->bf16 A-staging. A (f32 activations)
// is reg-staged (2 sets S1/S2 of 8 float4), converted, ds_write_b128 to the
// swizzled slot; B stays gl16 (pre-swizzled source col, linear dest).
// Mixed vmcnt ring (f32 set = 8 slots, B half-pair = 4): steady gates
// vmcnt(12) at P2/P4; prologue 8/16/8; tail clamps load indices to keep the
// queue uniform, then vmcnt(0). Every ds_write >= 2 barriers after its
// region's last read. z=0: Qw*0.125, z=1: Kw, z=2: VtG (C^T out).
// ---------------------------------------------------------------------------
__global__ __launch_bounds__(512, 1) void gemm8(const float* __restrict__ Qf,
                                                const float* __restrict__ Kf,
                                                const float* __restrict__ Vf,
                                                const bf16* __restrict__ WtQ,
                                                bf16* __restrict__ Qw,
                                                bf16* __restrict__ Kw,
                                                bf16* __restrict__ VtG) {
    __shared__ bf16 LA[2][256 * 64];
    __shared__ bf16 LB[2][256 * 64];
    char* LAB = (char*)LA;
    char* LBB = (char*)LB;
    int t = threadIdx.x;
    int z = blockIdx.z;
    const float* A = (z == 0) ? Qf : (z == 1) ? Kf : Vf;
    const bf16* Bt = WtQ + ((size_t)z << 20);
    int m0 = blockIdx.x * 256, n0 = blockIdx.y * 256;
    int wid = t >> 6, lane = t & 63;
    int wr = wid >> 2, wc = wid & 3, lr = lane & 15, lg = lane >> 4;
    const int sxl = (lr & 7) << 4;
    const int arow = wr * 128 + lr;
    const int brow = wc * 64 + lr;
    // B staging coords (gl16, pre-swizzled source col)
    const int c0 = t, c1 = t + 512;
    const int r0 = c0 >> 3, q0 = (c0 & 7) ^ (r0 & 7);
    const int r1 = c1 >> 3, q1 = (c1 & 7) ^ (r1 & 7);
    // A staging coords (f32 reg-stage): 4 segments of 8 floats
    int arw[4], aq[4], ahalf[4], alof[4];
#pragma unroll
    for (int j = 0; j < 4; j++) {
        int c = t + j * 512;          // 0..2047 over 256 rows x 8 segs
        int row = c >> 3, q = c & 7;
        arw[j] = row; aq[j] = q;
        ahalf[j] = row >> 7;
        int lrow = row & 127;
        alof[j] = (ahalf[j] << 14) + (((lrow * 128 + q * 16)) ^ ((lrow & 7) << 4));
    }

    f32x4 zero = {0.f, 0.f, 0.f, 0.f};
    f32x4 acc[8][4];
#pragma unroll
    for (int m = 0; m < 8; m++)
#pragma unroll
        for (int n = 0; n < 4; n++) acc[m][n] = zero;
    bf16x8 a[4][2], b0[2][2], b1[2][2];
    float4 S1[4][2], S2[4][2];

#define LOADF(SET, KT)                                                         \
    {                                                                          \
        _Pragma("unroll") for (int j = 0; j < 4; j++) {                        \
            const float* src = &A[(size_t)(m0 + arw[j]) * 1024 + (KT) * 64 + aq[j] * 8]; \
            SET[j][0] = *(const float4*)src;                                   \
            SET[j][1] = *(const float4*)(src + 4);                             \
        }                                                                      \
    }
#define DSW_A(BUF, SET)                                                        \
    {                                                                          \
        _Pragma("unroll") for (int j = 0; j < 4; j++) {                        \
            bf16x8 o;                                                          \
            o[0] = f2b(SET[j][0].x); o[1] = f2b(SET[j][0].y);                  \
            o[2] = f2b(SET[j][0].z); o[3] = f2b(SET[j][0].w);                  \
            o[4] = f2b(SET[j][1].x); o[5] = f2b(SET[j][1].y);                  \
            o[6] = f2b(SET[j][1].z); o[7] = f2b(SET[j][1].w);                  \
            *(bf16x8*)(LAB + (BUF) * 32768 + alof[j]) = o;                     \
        }                                                                      \
    }
#define STG_B2(BUF, KT)                                                        \
    gl16(&Bt[(size_t)(n0 + r0) * 1024 + (KT) * 64 + q0 * 8],                   \
         (void*)(LBB + (BUF) * 32768 + c0 * 16));                              \
    gl16(&Bt[(size_t)(n0 + r1) * 1024 + (KT) * 64 + q1 * 8],                   \
         (void*)(LBB + (BUF) * 32768 + c1 * 16));                              \
    gl16(&Bt[(size_t)(n0 + 128 + r0) * 1024 + (KT) * 64 + q0 * 8],             \
         (void*)(LBB + (BUF) * 32768 + 16384 + c0 * 16));                      \
    gl16(&Bt[(size_t)(n0 + 128 + r1) * 1024 + (KT) * 64 + q1 * 8],             \
         (void*)(LBB + (BUF) * 32768 + 16384 + c1 * 16));
#define RD_A(BUF, MH)                                                          \
    {                                                                          \
        _Pragma("unroll") for (int m = 0; m < 4; m++) {                        \
            int row = arow + (MH) * 64 + m * 16;                               \
            _Pragma("unroll") for (int ks = 0; ks < 2; ks++)                   \
                a[m][ks] = *(const bf16x8*)(LAB + (BUF) * 32768 +              \
                           ((row * 128 + ks * 64 + lg * 16) ^ sxl));           \
        }                                                                      \
    }
#define RD_B(BUF, NH, DST)                                                     \
    {                                                                          \
        _Pragma("unroll") for (int n = 0; n < 2; n++) {                        \
            int row = brow + (NH) * 32 + n * 16;                               \
            _Pragma("unroll") for (int ks = 0; ks < 2; ks++)                   \
                DST[n][ks] = *(const bf16x8*)(LBB + (BUF) * 32768 +            \
                             ((row * 128 + ks * 64 + lg * 16) ^ sxl));         \
        }                                                                      \
    }
#define MM(MH, NH, BB)                                                         \
    {                                                                          \
        _Pragma("unroll") for (int m = 0; m < 4; m++)                          \
        _Pragma("unroll") for (int n = 0; n < 2; n++)                          \
        _Pragma("unroll") for (int ks = 0; ks < 2; ks++)                       \
            acc[(MH) * 4 + m][(NH) * 2 + n] =                                  \
                mfma16(a[m][ks], BB[n][ks], acc[(MH) * 4 + m][(NH) * 2 + n]);  \
    }
#define PH_PRE                                                                 \
    __builtin_amdgcn_s_barrier();                                              \
    asm volatile("s_waitcnt lgkmcnt(0)" ::: "memory");                         \
    __builtin_amdgcn_sched_barrier(0);                                         \
    __builtin_amdgcn_s_setprio(1);
#define PH_POST                                                                \
    __builtin_amdgcn_s_setprio(0);                                             \
    __builtin_amdgcn_s_barrier();
#define GATE12                                                                 \
    __builtin_amdgcn_s_setprio(0);                                             \
    asm volatile("s_waitcnt vmcnt(12)" ::: "memory");                          \
    __builtin_amdgcn_s_barrier();

    // prologue
    LOADF(S1, 0);                                     // T0 : 8
    STG_B2(0, 0);                                     // +4
    STG_B2(1, 1);                                     // +4
    asm volatile("s_waitcnt vmcnt(8)" ::: "memory");  // T0 landed
    DSW_A(0, S1);                                     // tile0 -> LA buf0
    LOADF(S1, 1);                                     // T1 : 8
    LOADF(S2, 2);                                     // T2 : 8
    asm volatile("s_waitcnt vmcnt(16)" ::: "memory"); // B0,B1 landed
    asm volatile("s_waitcnt lgkmcnt(0)" ::: "memory");
    __builtin_amdgcn_s_barrier();                     // LA buf0 visible
    asm volatile("s_waitcnt vmcnt(8)" ::: "memory");  // T1 landed (T2 in flight)

    for (int i = 0; i < 7; i++) {
        int kt = 2 * i;
        int kt3 = (kt + 3 < 15) ? kt + 3 : 15;
        int kt4 = (kt + 4 < 15) ? kt + 4 : 15;
        // P1: compute buf0 MH0; ds_write A buf1 (tile kt+1); load S1 <- kt+3
        RD_A(0, 0); RD_B(0, 0, b0); RD_B(0, 1, b1);
        DSW_A(1, S1);
        LOADF(S1, kt3);
        PH_PRE; MM(0, 0, b0); MM(0, 1, b1); PH_POST;
        // P2: buf0 MH1; gl16 B buf0 (kt+2); gate
        RD_A(0, 1);
        STG_B2(0, kt + 2);
        PH_PRE; MM(1, 0, b0); MM(1, 1, b1); GATE12;
        // P3: buf1 MH0; ds_write A buf0 (tile kt+2); load S2 <- kt+4
        RD_A(1, 0); RD_B(1, 0, b0); RD_B(1, 1, b1);
        DSW_A(0, S2);
        LOADF(S2, kt4);
        PH_PRE; MM(0, 0, b0); MM(0, 1, b1); PH_POST;
        // P4: buf1 MH1; gl16 B buf1 (kt+3); gate
        RD_A(1, 1);
        STG_B2(1, kt + 3);
        PH_PRE; MM(1, 0, b0); MM(1, 1, b1); GATE12;
    }
    // tail: tiles 14 (buf0), 15 (buf1: A from S1)
    RD_A(0, 0); RD_B(0, 0, b0); RD_B(0, 1, b1);
    DSW_A(1, S1);
    PH_PRE; MM(0, 0, b0); MM(0, 1, b1); PH_POST;
    RD_A(0, 1);
    PH_PRE; MM(1, 0, b0); MM(1, 1, b1);
    __builtin_amdgcn_s_setprio(0);
    asm volatile("s_waitcnt vmcnt(0)" ::: "memory");
    __builtin_amdgcn_s_barrier();
    RD_A(1, 0); RD_B(1, 0, b0); RD_B(1, 1, b1);
    PH_PRE; MM(0, 0, b0); MM(0, 1, b1); PH_POST;
    RD_A(1, 1);
    PH_PRE; MM(1, 0, b0); MM(1, 1, b1);
    __builtin_amdgcn_s_setprio(0);
#undef LOADF
#undef DSW_A
#undef STG_B2
#undef RD_A
#undef RD_B
#undef MM
#undef PH_PRE
#undef PH_POST
#undef GATE12
#pragma unroll
    for (int m = 0; m < 8; m++) {
        int rowg = m0 + wr * 128 + m * 16 + lg * 4;
#pragma unroll
        for (int n = 0; n < 4; n++) {
            int colg = n0 + wc * 64 + n * 16 + lr;
            if (z == 2) {
                bf16x4 o;
#pragma unroll
                for (int j = 0; j < 4; j++) o[j] = f2b(acc[m][n][j]);
                *(bf16x4*)&VtG[(size_t)colg * 4096 + rowg] = o;
            } else {
                bf16* C = (z == 0) ? Qw : Kw;
                float sc = (z == 0) ? 0.125f : 1.0f;
#pragma unroll
                for (int j = 0; j < 4; j++)
                    C[(size_t)(rowg + j) * 1024 + colg] = f2b(acc[m][n][j] * sc);
            }
        }
    }
}

// ---------------------------------------------------------------------------
// Merged output + attention_weights GEMM (proven single-buffer, BK=64).
// ---------------------------------------------------------------------------
__global__ __launch_bounds__(256, 3) void gemm_oa(const bf16* __restrict__ CTX,
                                                  const bf16* __restrict__ WtO,
                                                  float* __restrict__ out,
                                                  const bf16* __restrict__ Qw,
                                                  const bf16* __restrict__ Kw,
                                                  float* __restrict__ aw,
                                                  const int* __restrict__ maskp) {
    __shared__ bf16 As[128 * 64];
    __shared__ bf16 Bs[128 * 64];
    char* AsB = (char*)As;
    char* BsB = (char*)Bs;
    int t = threadIdx.x;
    int z = blockIdx.z;
    int bx = blockIdx.x;
    int m0, n0 = blockIdx.y * 128;
    const bf16* A;
    const bf16* Bt;
    float* C;
    const int* mask = nullptr;
    if (z == 0) {
        m0 = bx * 128;
        A = CTX; Bt = WtO; C = out;
    } else {
        int b = bx >> 3;
        m0 = (bx & 7) * 128;
        A = Qw + ((size_t)b << 20); Bt = Kw + ((size_t)b << 20);
        C = aw + ((size_t)b << 20); mask = maskp + b * 1024;
    }
    int wid = t >> 6, lane = t & 63;
    int wr = wid >> 1, wc = wid & 1, lr = lane & 15, lg = lane >> 4;
    f32x4 zero = {0.f, 0.f, 0.f, 0.f};
    f32x4 acc[4][4];
#pragma unroll
    for (int m = 0; m < 4; m++)
#pragma unroll
        for (int n = 0; n < 4; n++) acc[m][n] = zero;

    for (int k0 = 0; k0 < 1024; k0 += 64) {
        __syncthreads();
#pragma unroll
        for (int i = 0; i < 4; i++) {
            int c = wid * 256 + i * 64 + lane;
            int row = c >> 3, q = (c & 7) ^ (row & 7);
            gl16(&A[(size_t)(m0 + row) * 1024 + k0 + q * 8], (void*)&As[c * 8]);
            gl16(&Bt[(size_t)(n0 + row) * 1024 + k0 + q * 8], (void*)&Bs[c * 8]);
        }
        __syncthreads();
#pragma unroll
        for (int kk = 0; kk < 2; kk++) {
            bf16x8 af[4], bfr[4];
#pragma unroll
            for (int m = 0; m < 4; m++) {
                int row = wr * 64 + m * 16 + lr;
                af[m] = *(const bf16x8*)(AsB + ((row * 128 + kk * 64 + lg * 16) ^ ((row & 7) << 4)));
            }
#pragma unroll
            for (int n = 0; n < 4; n++) {
                int row = wc * 64 + n * 16 + lr;
                bfr[n] = *(const bf16x8*)(BsB + ((row * 128 + kk * 64 + lg * 16) ^ ((row & 7) << 4)));
            }
#pragma unroll
            for (int m = 0; m < 4; m++)
#pragma unroll
                for (int n = 0; n < 4; n++) acc[m][n] = mfma16(af[m], bfr[n], acc[m][n]);
        }
    }
#pragma unroll
    for (int n = 0; n < 4; n++) {
        int colg = n0 + wc * 64 + n * 16 + lr;
        int mk = (z == 1) ? mask[colg] : 0;
#pragma unroll
        for (int m = 0; m < 4; m++) {
            int rowg = m0 + wr * 64 + m * 16 + lg * 4;
#pragma unroll
            for (int j = 0; j < 4; j++) {
                float v = acc[m][n][j];
                size_t idx = (size_t)(rowg + j) * 1024 + colg;
                if (z == 0) C[idx] = v;
                else C[idx] = mk ? NEGV : v * (1.f / 16.f);
            }
        }
    }
}

// ---------------------------------------------------------------------------
// Flash attention v6 (unchanged): no-max unnormalized softmax, per-lane
// partial sums, K dbuf, XCD-locality swizzle.
// ---------------------------------------------------------------------------
__global__ __launch_bounds__(256, 4) void flash_k(const bf16* __restrict__ Q,
                                                  const bf16* __restrict__ K,
                                                  const bf16* __restrict__ VT,
                                                  bf16* __restrict__ CTX,
                                                  const int* __restrict__ maskp) {
    __shared__ bf16 Ks[2][64 * 64];
    __shared__ bf16 Vs[64 * 64];
    __shared__ bf16 Ps[4][16 * 64];
    __shared__ float biasS[1024];
    int raw = blockIdx.x;
    int idx = raw >> 3;
    int bh = (raw & 7) * 8 + (idx & 7);
    int qt = idx >> 3;
    int b = bh >> 4, h = bh & 15;
    int t = threadIdx.x, wid = t >> 6, lane = t & 63;
    int lr = lane & 15, lg = lane >> 4;
    int qbase = qt * 64 + wid * 16;
    const size_t bS = (size_t)b * 1024;
    char* KsB = (char*)Ks;
    char* VsB = (char*)Vs;
    char* PsW = (char*)&Ps[wid][0];
    const int sxl = (lr & 7) << 4;

    {
        int4 mv = *(const int4*)&maskp[b * 1024 + t * 4];
        float4 bv;
        const float NB = NEGV * LOG2E;
        bv.x = mv.x ? NB : 0.f; bv.y = mv.y ? NB : 0.f;
        bv.z = mv.z ? NB : 0.f; bv.w = mv.w ? NB : 0.f;
        *(float4*)&biasS[t * 4] = bv;
    }

    bf16x8 qf[2];
#pragma unroll
    for (int c = 0; c < 2; c++)
        qf[c] = *(const bf16x8*)&Q[(bS + qbase + lr) * 1024 + h * 64 + c * 32 + lg * 8];

    f32x4 zero = {0.f, 0.f, 0.f, 0.f};
    f32x4 acc[4];
#pragma unroll
    for (int d = 0; d < 4; d++) acc[d] = zero;
    float lsum = 0.f;

    const bf16* Kbase = K + bS * 1024 + h * 64;
    const bf16* Vbase = VT + (size_t)(h * 64) * 4096 + bS;

    int c0 = t, c1 = t + 256;
    int kr0 = c0 >> 3, kq0 = c0 & 7, kr1 = c1 >> 3, kq1 = c1 & 7;
    const int kw0 = (kr0 * 128 + kq0 * 16) ^ ((kr0 & 7) << 4);
    const int kw1 = (kr1 * 128 + kq1 * 16) ^ ((kr1 & 7) << 4);

    {
        bf16x8 t0 = *(const bf16x8*)&Kbase[(size_t)kr0 * 1024 + kq0 * 8];
        bf16x8 t1 = *(const bf16x8*)&Kbase[(size_t)kr1 * 1024 + kq1 * 8];
        *(bf16x8*)(KsB + kw0) = t0;
        *(bf16x8*)(KsB + kw1) = t1;
    }
    bf16x8 kg[2], vg[2];
    vg[0] = *(const bf16x8*)&Vbase[(size_t)kr0 * 4096 + kq0 * 8];
    vg[1] = *(const bf16x8*)&Vbase[(size_t)kr1 * 4096 + kq1 * 8];
    kg[0] = *(const bf16x8*)&Kbase[(size_t)(64 + kr0) * 1024 + kq0 * 8];
    kg[1] = *(const bf16x8*)&Kbase[(size_t)(64 + kr1) * 1024 + kq1 * 8];

    int cur = 0;
    for (int kt = 0; kt < 16; kt++) {
        __syncthreads();
        *(bf16x8*)(VsB + kw0) = vg[0];
        *(bf16x8*)(VsB + kw1) = vg[1];
        if (kt < 15) {
            *(bf16x8*)(KsB + (cur ^ 1) * 8192 + kw0) = kg[0];
            *(bf16x8*)(KsB + (cur ^ 1) * 8192 + kw1) = kg[1];
            size_t ko = (size_t)(kt + 1) * 64;
            vg[0] = *(const bf16x8*)&Vbase[(size_t)kr0 * 4096 + ko + kq0 * 8];
            vg[1] = *(const bf16x8*)&Vbase[(size_t)kr1 * 4096 + ko + kq1 * 8];
            if (kt < 14) {
                kg[0] = *(const bf16x8*)&Kbase[(ko + 64 + kr0) * 1024 + kq0 * 8];
                kg[1] = *(const bf16x8*)&Kbase[(ko + 64 + kr1) * 1024 + kq1 * 8];
            }
        }
        f32x4 s[4];
        __builtin_amdgcn_s_setprio(1);
#pragma unroll
        for (int n = 0; n < 4; n++) {
            int row = n * 16 + lr;
            bf16x8 kf0 = *(const bf16x8*)(KsB + cur * 8192 + ((row * 128 + lg * 16) ^ sxl));
            bf16x8 kf1 = *(const bf16x8*)(KsB + cur * 8192 + ((row * 128 + 64 + lg * 16) ^ sxl));
            f32x4 zz = zero;
            zz = mfma16(kf0, qf[0], zz);
            zz = mfma16(kf1, qf[1], zz);
            s[n] = zz;
        }
        __builtin_amdgcn_s_setprio(0);
        __syncthreads();
        float r0 = 0.f, r1 = 0.f, r2 = 0.f, r3 = 0.f;
#pragma unroll
        for (int n = 0; n < 4; n++) {
            float4 bv = *(const float4*)&biasS[kt * 64 + n * 16 + lg * 4];
            float p0 = __builtin_exp2f(__builtin_fmaf(s[n][0], LOG2E, bv.x));
            float p1 = __builtin_exp2f(__builtin_fmaf(s[n][1], LOG2E, bv.y));
            float p2 = __builtin_exp2f(__builtin_fmaf(s[n][2], LOG2E, bv.z));
            float p3 = __builtin_exp2f(__builtin_fmaf(s[n][3], LOG2E, bv.w));
            r0 += p0; r1 += p1; r2 += p2; r3 += p3;
            bf16x4 o;
            o[0] = (bf16)p0; o[1] = (bf16)p1; o[2] = (bf16)p2; o[3] = (bf16)p3;
            *(bf16x4*)(PsW + ((lr * 128 + n * 32 + lg * 8) ^ sxl)) = o;
        }
        lsum += (r0 + r1) + (r2 + r3);
        __builtin_amdgcn_s_setprio(1);
#pragma unroll
        for (int c = 0; c < 2; c++) {
            bf16x8 pa = *(const bf16x8*)(PsW + ((lr * 128 + c * 64 + lg * 16) ^ sxl));
#pragma unroll
            for (int d = 0; d < 4; d++) {
                int row = d * 16 + lr;
                bf16x8 vb = *(const bf16x8*)(VsB + ((row * 128 + c * 64 + lg * 16) ^ ((row & 7) << 4)));
                acc[d] = mfma16(pa, vb, acc[d]);
            }
        }
        __builtin_amdgcn_s_setprio(0);
        cur ^= 1;
    }
    lsum += __shfl_xor(lsum, 16);
    lsum += __shfl_xor(lsum, 32);
    float lb[4];
#pragma unroll
    for (int j = 0; j < 4; j++) lb[j] = __shfl(lsum, lg * 4 + j);
#pragma unroll
    for (int j = 0; j < 4; j++) {
        float inv = 1.f / lb[j];
#pragma unroll
        for (int d = 0; d < 4; d++)
            CTX[(bS + qbase + lg * 4 + j) * 1024 + h * 64 + d * 16 + lr] = f2b(acc[d][j] * inv);
    }
}

extern "C" void kernel_launch(void* const* d_in, const int* in_sizes, int n_in,
                              void* d_out, int out_size, void* d_ws, size_t ws_size,
                              hipStream_t stream) {
    const float* queries = (const float*)d_in[0];
    const float* keys    = (const float*)d_in[1];
    const float* values  = (const float*)d_in[2];
    const float* Wq = (const float*)d_in[3];
    const float* Wk = (const float*)d_in[4];
    const float* Wv = (const float*)d_in[5];
    const float* Wo = (const float*)d_in[6];
    const int* mask = (const int*)d_in[7];

    float* out = (float*)d_out;                       // [4,1024,1024]
    float* aw  = out + ((size_t)4 << 20);             // [4,1024,1024]

    bf16* wsb = (bf16*)d_ws;
    bf16* WtQ = wsb;                                  // transposed weights (Q,K,V,O)
    bf16* CTX = wsb + ((size_t)4 << 20);
    bf16* Qw  = wsb + ((size_t)8 << 20);
    bf16* Kw  = wsb + ((size_t)12 << 20);
    bf16* VtG = wsb + ((size_t)16 << 20);             // [1024][4096] V transposed

    prep<<<dim3(1024), 256, 0, stream>>>(Wq, Wk, Wv, Wo, WtQ);
    gemm8<<<dim3(16, 4, 3), 512, 0, stream>>>(queries, keys, values, WtQ, Qw, Kw, VtG);
    flash_k<<<dim3(1024), 256, 0, stream>>>(Qw, Kw, VtG, CTX, mask);
    gemm_oa<<<dim3(32, 8, 2), 256, 0, stream>>>(CTX, WtQ + ((size_t)3 << 20), out,
                                                Qw, Kw, aw, mask);
}

// Round 12
// 116.673 us; speedup vs baseline: 1.9091x; 1.9091x over previous
//
#include <hip/hip_runtime.h>
#include <hip/hip_bf16.h>

typedef __bf16 bf16;
typedef __attribute__((ext_vector_type(8))) __bf16 bf16x8;
typedef __attribute__((ext_vector_type(4))) __bf16 bf16x4;
typedef __attribute__((ext_vector_type(4))) float f32x4;

#define NEGV (-1e18f)
#define LOG2E 1.4426950408889634f

__device__ __forceinline__ bf16 f2b(float f) {
    unsigned u = __builtin_bit_cast(unsigned, f);
    u += 0x7fffu + ((u >> 16) & 1u);
    unsigned short h = (unsigned short)(u >> 16);
    return __builtin_bit_cast(bf16, h);
}

__device__ __forceinline__ f32x4 mfma16(bf16x8 a, bf16x8 b, f32x4 c) {
    return __builtin_amdgcn_mfma_f32_16x16x32_bf16(a, b, c, 0, 0, 0);
}

__device__ __forceinline__ void gl16(const void* g, void* l) {
    __builtin_amdgcn_global_load_lds((const __attribute__((address_space(1))) void*)g,
                                     (__attribute__((address_space(3))) void*)l, 16, 0, 0);
}

// ---------------------------------------------------------------------------
// prep: merged weight-transpose+convert (blocks >= 6144) and activation
// f32->bf16 convert (blocks < 6144). One launch.
// ---------------------------------------------------------------------------
__global__ __launch_bounds__(256) void prep(const float* __restrict__ Qf,
                                            const float* __restrict__ Kf,
                                            const float* __restrict__ Vf,
                                            const float* __restrict__ W0,
                                            const float* __restrict__ W1,
                                            const float* __restrict__ W2,
                                            const float* __restrict__ W3,
                                            bf16* __restrict__ Qa,
                                            bf16* __restrict__ Ka,
                                            bf16* __restrict__ Va,
                                            bf16* __restrict__ Wout) {
    __shared__ float tile[64][65];
    int bx = blockIdx.x;
    int t = threadIdx.x;
    if (bx < 6144) {
        int z = bx >> 11, x = bx & 2047;
        const float* in = (z == 0) ? Qf : (z == 1) ? Kf : Vf;
        bf16* out = (z == 0) ? Qa : (z == 1) ? Ka : Va;
        size_t i = ((size_t)x * 256 + t) * 8;
        float4 a = *(const float4*)&in[i];
        float4 b = *(const float4*)&in[i + 4];
        bf16x8 o;
        o[0] = f2b(a.x); o[1] = f2b(a.y); o[2] = f2b(a.z); o[3] = f2b(a.w);
        o[4] = f2b(b.x); o[5] = f2b(b.y); o[6] = f2b(b.z); o[7] = f2b(b.w);
        *(bf16x8*)&out[i] = o;
        return;
    }
    int w = bx - 6144;
    int z = w >> 8;
    const float* Ws[4] = {W0, W1, W2, W3};
    const float* W = Ws[z];
    bf16* O = Wout + ((size_t)z << 20);
    int k0 = (w & 15) * 64, n0 = ((w >> 4) & 15) * 64;
#pragma unroll
    for (int p = 0; p < 4; p++) {
        int r = (t >> 4) + p * 16, c = (t & 15) * 4;
        float4 v = *(const float4*)&W[(size_t)(k0 + r) * 1024 + n0 + c];
        tile[r][c] = v.x; tile[r][c + 1] = v.y; tile[r][c + 2] = v.z; tile[r][c + 3] = v.w;
    }
    __syncthreads();
#pragma unroll
    for (int p = 0; p < 4; p++) {
        int r = (t >> 4) + p * 16, c = (t & 15) * 4;
        bf16x4 o;
        o[0] = f2b(tile[c][r]); o[1] = f2b(tile[c + 1][r]);
        o[2] = f2b(tile[c + 2][r]); o[3] = f2b(tile[c + 3][r]);
        *(bf16x4*)&O[(size_t)(n0 + r) * 1024 + k0 + c] = o;
    }
}

// ---------------------------------------------------------------------------
// 8-phase 256x256 GEMM (T2+T3+T4+T5), staggered race-free stage ring
// (verified R8/R9: absmax clean, 43.4us). z=0: Qw*0.125, z=1: Kw, z=2: VtG.
// ---------------------------------------------------------------------------
__global__ __launch_bounds__(512, 1) void gemm8(const bf16* __restrict__ Qa,
                                                const bf16* __restrict__ Ka,
                                                const bf16* __restrict__ Va,
                                                const bf16* __restrict__ WtQ,
                                                bf16* __restrict__ Qw,
                                                bf16* __restrict__ Kw,
                                                bf16* __restrict__ VtG) {
    __shared__ bf16 LA[2][256 * 64];
    __shared__ bf16 LB[2][256 * 64];
    char* LAB = (char*)LA;
    char* LBB = (char*)LB;
    int t = threadIdx.x;
    int z = blockIdx.z;
    const bf16* A = (z == 0) ? Qa : (z == 1) ? Ka : Va;
    const bf16* Bt = WtQ + ((size_t)z << 20);
    int m0 = blockIdx.x * 256, n0 = blockIdx.y * 256;
    int wid = t >> 6, lane = t & 63;
    int wr = wid >> 2, wc = wid & 3, lr = lane & 15, lg = lane >> 4;
    const int sxl = (lr & 7) << 4;
    const int arow = wr * 128 + lr;
    const int brow = wc * 64 + lr;
    const int c0 = t, c1 = t + 512;
    const int r0 = c0 >> 3, q0 = (c0 & 7) ^ (r0 & 7);
    const int r1 = c1 >> 3, q1 = (c1 & 7) ^ (r1 & 7);

    f32x4 zero = {0.f, 0.f, 0.f, 0.f};
    f32x4 acc[8][4];
#pragma unroll
    for (int m = 0; m < 8; m++)
#pragma unroll
        for (int n = 0; n < 4; n++) acc[m][n] = zero;
    bf16x8 a[4][2], b0[2][2], b1[2][2];

#define STG_A(BUF, HALF, KT)                                                   \
    gl16(&A[(size_t)(m0 + (HALF) * 128 + r0) * 1024 + (KT) * 64 + q0 * 8],     \
         (void*)(LAB + (BUF) * 32768 + (HALF) * 16384 + c0 * 16));             \
    gl16(&A[(size_t)(m0 + (HALF) * 128 + r1) * 1024 + (KT) * 64 + q1 * 8],     \
         (void*)(LAB + (BUF) * 32768 + (HALF) * 16384 + c1 * 16));
#define STG_B(BUF, HALF, KT)                                                   \
    gl16(&Bt[(size_t)(n0 + (HALF) * 128 + r0) * 1024 + (KT) * 64 + q0 * 8],    \
         (void*)(LBB + (BUF) * 32768 + (HALF) * 16384 + c0 * 16));             \
    gl16(&Bt[(size_t)(n0 + (HALF) * 128 + r1) * 1024 + (KT) * 64 + q1 * 8],    \
         (void*)(LBB + (BUF) * 32768 + (HALF) * 16384 + c1 * 16));
#define RD_A(BUF, MH)                                                          \
    {                                                                          \
        _Pragma("unroll") for (int m = 0; m < 4; m++) {                        \
            int row = arow + (MH) * 64 + m * 16;                               \
            _Pragma("unroll") for (int ks = 0; ks < 2; ks++)                   \
                a[m][ks] = *(const bf16x8*)(LAB + (BUF) * 32768 +              \
                           ((row * 128 + ks * 64 + lg * 16) ^ sxl));           \
        }                                                                      \
    }
#define RD_B(BUF, NH, DST)                                                     \
    {                                                                          \
        _Pragma("unroll") for (int n = 0; n < 2; n++) {                        \
            int row = brow + (NH) * 32 + n * 16;                               \
            _Pragma("unroll") for (int ks = 0; ks < 2; ks++)                   \
                DST[n][ks] = *(const bf16x8*)(LBB + (BUF) * 32768 +            \
                             ((row * 128 + ks * 64 + lg * 16) ^ sxl));         \
        }                                                                      \
    }
#define MM(MH, NH, BB)                                                         \
    {                                                                          \
        _Pragma("unroll") for (int m = 0; m < 4; m++)                          \
        _Pragma("unroll") for (int n = 0; n < 2; n++)                          \
        _Pragma("unroll") for (int ks = 0; ks < 2; ks++)                       \
            acc[(MH) * 4 + m][(NH) * 2 + n] =                                  \
                mfma16(a[m][ks], BB[n][ks], acc[(MH) * 4 + m][(NH) * 2 + n]);  \
    }
#define PH_PRE                                                                 \
    __builtin_amdgcn_s_barrier();                                              \
    asm volatile("s_waitcnt lgkmcnt(0)" ::: "memory");                         \
    __builtin_amdgcn_sched_barrier(0);                                         \
    __builtin_amdgcn_s_setprio(1);
#define PH_POST                                                                \
    __builtin_amdgcn_s_setprio(0);                                             \
    __builtin_amdgcn_s_barrier();
#define VM4_BAR                                                                \
    __builtin_amdgcn_s_setprio(0);                                             \
    asm volatile("s_waitcnt vmcnt(4)" ::: "memory");                           \
    __builtin_amdgcn_s_barrier();

    STG_A(0, 0, 0); STG_A(0, 1, 0); STG_B(0, 0, 0); STG_B(0, 1, 0);
    STG_B(1, 0, 1); STG_B(1, 1, 1);
    asm volatile("s_waitcnt vmcnt(4)" ::: "memory");
    __builtin_amdgcn_s_barrier();

    for (int i = 0; i < 7; i++) {
        int kt = 2 * i;
        RD_A(0, 0); RD_B(0, 0, b0); STG_A(1, 0, kt + 1);
        PH_PRE; MM(0, 0, b0); PH_POST;
        RD_B(0, 1, b1); STG_A(1, 1, kt + 1);
        PH_PRE; MM(0, 1, b1); PH_POST;
        RD_A(0, 1); STG_B(0, 0, kt + 2);
        PH_PRE; MM(1, 0, b0); PH_POST;
        STG_B(0, 1, kt + 2);
        PH_PRE; MM(1, 1, b1); VM4_BAR;
        RD_A(1, 0); RD_B(1, 0, b0); STG_A(0, 0, kt + 2);
        PH_PRE; MM(0, 0, b0); PH_POST;
        RD_B(1, 1, b1); STG_A(0, 1, kt + 2);
        PH_PRE; MM(0, 1, b1); PH_POST;
        RD_A(1, 1); STG_B(1, 0, kt + 3);
        PH_PRE; MM(1, 0, b0); PH_POST;
        STG_B(1, 1, kt + 3);
        PH_PRE; MM(1, 1, b1); VM4_BAR;
    }
    RD_A(0, 0); RD_B(0, 0, b0); STG_A(1, 0, 15);
    PH_PRE; MM(0, 0, b0); PH_POST;
    RD_B(0, 1, b1); STG_A(1, 1, 15);
    PH_PRE; MM(0, 1, b1); PH_POST;
    RD_A(0, 1);
    PH_PRE; MM(1, 0, b0); PH_POST;
    PH_PRE; MM(1, 1, b1);
    __builtin_amdgcn_s_setprio(0);
    asm volatile("s_waitcnt vmcnt(0)" ::: "memory");
    __builtin_amdgcn_s_barrier();
    RD_A(1, 0); RD_B(1, 0, b0);
    PH_PRE; MM(0, 0, b0); PH_POST;
    RD_B(1, 1, b1);
    PH_PRE; MM(0, 1, b1); PH_POST;
    RD_A(1, 1);
    PH_PRE; MM(1, 0, b0); PH_POST;
    PH_PRE; MM(1, 1, b1);
    __builtin_amdgcn_s_setprio(0);
#undef STG_A
#undef STG_B
#undef RD_A
#undef RD_B
#undef MM
#undef PH_PRE
#undef PH_POST
#undef VM4_BAR
#pragma unroll
    for (int m = 0; m < 8; m++) {
        int rowg = m0 + wr * 128 + m * 16 + lg * 4;
#pragma unroll
        for (int n = 0; n < 4; n++) {
            int colg = n0 + wc * 64 + n * 16 + lr;
            if (z == 2) {
                bf16x4 o;
#pragma unroll
                for (int j = 0; j < 4; j++) o[j] = f2b(acc[m][n][j]);
                *(bf16x4*)&VtG[(size_t)colg * 4096 + rowg] = o;
            } else {
                bf16* C = (z == 0) ? Qw : Kw;
                float sc = (z == 0) ? 0.125f : 1.0f;
#pragma unroll
                for (int j = 0; j < 4; j++)
                    C[(size_t)(rowg + j) * 1024 + colg] = f2b(acc[m][n][j] * sc);
            }
        }
    }
}

// ---------------------------------------------------------------------------
// Merged output + attention_weights GEMM (proven single-buffer, BK=64).
// ---------------------------------------------------------------------------
__global__ __launch_bounds__(256, 3) void gemm_oa(const bf16* __restrict__ CTX,
                                                  const bf16* __restrict__ WtO,
                                                  float* __restrict__ out,
                                                  const bf16* __restrict__ Qw,
                                                  const bf16* __restrict__ Kw,
                                                  float* __restrict__ aw,
                                                  const int* __restrict__ maskp) {
    __shared__ bf16 As[128 * 64];
    __shared__ bf16 Bs[128 * 64];
    char* AsB = (char*)As;
    char* BsB = (char*)Bs;
    int t = threadIdx.x;
    int z = blockIdx.z;
    int bx = blockIdx.x;
    int m0, n0 = blockIdx.y * 128;
    const bf16* A;
    const bf16* Bt;
    float* C;
    const int* mask = nullptr;
    if (z == 0) {
        m0 = bx * 128;
        A = CTX; Bt = WtO; C = out;
    } else {
        int b = bx >> 3;
        m0 = (bx & 7) * 128;
        A = Qw + ((size_t)b << 20); Bt = Kw + ((size_t)b << 20);
        C = aw + ((size_t)b << 20); mask = maskp + b * 1024;
    }
    int wid = t >> 6, lane = t & 63;
    int wr = wid >> 1, wc = wid & 1, lr = lane & 15, lg = lane >> 4;
    f32x4 zero = {0.f, 0.f, 0.f, 0.f};
    f32x4 acc[4][4];
#pragma unroll
    for (int m = 0; m < 4; m++)
#pragma unroll
        for (int n = 0; n < 4; n++) acc[m][n] = zero;

    for (int k0 = 0; k0 < 1024; k0 += 64) {
        __syncthreads();
#pragma unroll
        for (int i = 0; i < 4; i++) {
            int c = wid * 256 + i * 64 + lane;
            int row = c >> 3, q = (c & 7) ^ (row & 7);
            gl16(&A[(size_t)(m0 + row) * 1024 + k0 + q * 8], (void*)&As[c * 8]);
            gl16(&Bt[(size_t)(n0 + row) * 1024 + k0 + q * 8], (void*)&Bs[c * 8]);
        }
        __syncthreads();
#pragma unroll
        for (int kk = 0; kk < 2; kk++) {
            bf16x8 af[4], bfr[4];
#pragma unroll
            for (int m = 0; m < 4; m++) {
                int row = wr * 64 + m * 16 + lr;
                af[m] = *(const bf16x8*)(AsB + ((row * 128 + kk * 64 + lg * 16) ^ ((row & 7) << 4)));
            }
#pragma unroll
            for (int n = 0; n < 4; n++) {
                int row = wc * 64 + n * 16 + lr;
                bfr[n] = *(const bf16x8*)(BsB + ((row * 128 + kk * 64 + lg * 16) ^ ((row & 7) << 4)));
            }
#pragma unroll
            for (int m = 0; m < 4; m++)
#pragma unroll
                for (int n = 0; n < 4; n++) acc[m][n] = mfma16(af[m], bfr[n], acc[m][n]);
        }
    }
#pragma unroll
    for (int n = 0; n < 4; n++) {
        int colg = n0 + wc * 64 + n * 16 + lr;
        int mk = (z == 1) ? mask[colg] : 0;
#pragma unroll
        for (int m = 0; m < 4; m++) {
            int rowg = m0 + wr * 64 + m * 16 + lg * 4;
#pragma unroll
            for (int j = 0; j < 4; j++) {
                float v = acc[m][n][j];
                size_t idx = (size_t)(rowg + j) * 1024 + colg;
                if (z == 0) C[idx] = v;
                else C[idx] = mk ? NEGV : v * (1.f / 16.f);
            }
        }
    }
}

// ---------------------------------------------------------------------------
// Flash attention v6: no-max unnormalized softmax, per-lane partial sums,
// K dbuf, XCD-locality swizzle.
// ---------------------------------------------------------------------------
__global__ __launch_bounds__(256, 4) void flash_k(const bf16* __restrict__ Q,
                                                  const bf16* __restrict__ K,
                                                  const bf16* __restrict__ VT,
                                                  bf16* __restrict__ CTX,
                                                  const int* __restrict__ maskp) {
    __shared__ bf16 Ks[2][64 * 64];
    __shared__ bf16 Vs[64 * 64];
    __shared__ bf16 Ps[4][16 * 64];
    __shared__ float biasS[1024];
    int raw = blockIdx.x;
    int idx = raw >> 3;
    int bh = (raw & 7) * 8 + (idx & 7);
    int qt = idx >> 3;
    int b = bh >> 4, h = bh & 15;
    int t = threadIdx.x, wid = t >> 6, lane = t & 63;
    int lr = lane & 15, lg = lane >> 4;
    int qbase = qt * 64 + wid * 16;
    const size_t bS = (size_t)b * 1024;
    char* KsB = (char*)Ks;
    char* VsB = (char*)Vs;
    char* PsW = (char*)&Ps[wid][0];
    const int sxl = (lr & 7) << 4;

    {
        int4 mv = *(const int4*)&maskp[b * 1024 + t * 4];
        float4 bv;
        const float NB = NEGV * LOG2E;
        bv.x = mv.x ? NB : 0.f; bv.y = mv.y ? NB : 0.f;
        bv.z = mv.z ? NB : 0.f; bv.w = mv.w ? NB : 0.f;
        *(float4*)&biasS[t * 4] = bv;
    }

    bf16x8 qf[2];
#pragma unroll
    for (int c = 0; c < 2; c++)
        qf[c] = *(const bf16x8*)&Q[(bS + qbase + lr) * 1024 + h * 64 + c * 32 + lg * 8];

    f32x4 zero = {0.f, 0.f, 0.f, 0.f};
    f32x4 acc[4];
#pragma unroll
    for (int d = 0; d < 4; d++) acc[d] = zero;
    float lsum = 0.f;

    const bf16* Kbase = K + bS * 1024 + h * 64;
    const bf16* Vbase = VT + (size_t)(h * 64) * 4096 + bS;

    int c0 = t, c1 = t + 256;
    int kr0 = c0 >> 3, kq0 = c0 & 7, kr1 = c1 >> 3, kq1 = c1 & 7;
    const int kw0 = (kr0 * 128 + kq0 * 16) ^ ((kr0 & 7) << 4);
    const int kw1 = (kr1 * 128 + kq1 * 16) ^ ((kr1 & 7) << 4);

    {
        bf16x8 t0 = *(const bf16x8*)&Kbase[(size_t)kr0 * 1024 + kq0 * 8];
        bf16x8 t1 = *(const bf16x8*)&Kbase[(size_t)kr1 * 1024 + kq1 * 8];
        *(bf16x8*)(KsB + kw0) = t0;
        *(bf16x8*)(KsB + kw1) = t1;
    }
    bf16x8 kg[2], vg[2];
    vg[0] = *(const bf16x8*)&Vbase[(size_t)kr0 * 4096 + kq0 * 8];
    vg[1] = *(const bf16x8*)&Vbase[(size_t)kr1 * 4096 + kq1 * 8];
    kg[0] = *(const bf16x8*)&Kbase[(size_t)(64 + kr0) * 1024 + kq0 * 8];
    kg[1] = *(const bf16x8*)&Kbase[(size_t)(64 + kr1) * 1024 + kq1 * 8];

    int cur = 0;
    for (int kt = 0; kt < 16; kt++) {
        __syncthreads();
        *(bf16x8*)(VsB + kw0) = vg[0];
        *(bf16x8*)(VsB + kw1) = vg[1];
        if (kt < 15) {
            *(bf16x8*)(KsB + (cur ^ 1) * 8192 + kw0) = kg[0];
            *(bf16x8*)(KsB + (cur ^ 1) * 8192 + kw1) = kg[1];
            size_t ko = (size_t)(kt + 1) * 64;
            vg[0] = *(const bf16x8*)&Vbase[(size_t)kr0 * 4096 + ko + kq0 * 8];
            vg[1] = *(const bf16x8*)&Vbase[(size_t)kr1 * 4096 + ko + kq1 * 8];
            if (kt < 14) {
                kg[0] = *(const bf16x8*)&Kbase[(ko + 64 + kr0) * 1024 + kq0 * 8];
                kg[1] = *(const bf16x8*)&Kbase[(ko + 64 + kr1) * 1024 + kq1 * 8];
            }
        }
        f32x4 s[4];
        __builtin_amdgcn_s_setprio(1);
#pragma unroll
        for (int n = 0; n < 4; n++) {
            int row = n * 16 + lr;
            bf16x8 kf0 = *(const bf16x8*)(KsB + cur * 8192 + ((row * 128 + lg * 16) ^ sxl));
            bf16x8 kf1 = *(const bf16x8*)(KsB + cur * 8192 + ((row * 128 + 64 + lg * 16) ^ sxl));
            f32x4 zz = zero;
            zz = mfma16(kf0, qf[0], zz);
            zz = mfma16(kf1, qf[1], zz);
            s[n] = zz;
        }
        __builtin_amdgcn_s_setprio(0);
        __syncthreads();
        float r0 = 0.f, r1 = 0.f, r2 = 0.f, r3 = 0.f;
#pragma unroll
        for (int n = 0; n < 4; n++) {
            float4 bv = *(const float4*)&biasS[kt * 64 + n * 16 + lg * 4];
            float p0 = __builtin_exp2f(__builtin_fmaf(s[n][0], LOG2E, bv.x));
            float p1 = __builtin_exp2f(__builtin_fmaf(s[n][1], LOG2E, bv.y));
            float p2 = __builtin_exp2f(__builtin_fmaf(s[n][2], LOG2E, bv.z));
            float p3 = __builtin_exp2f(__builtin_fmaf(s[n][3], LOG2E, bv.w));
            r0 += p0; r1 += p1; r2 += p2; r3 += p3;
            bf16x4 o;
            o[0] = (bf16)p0; o[1] = (bf16)p1; o[2] = (bf16)p2; o[3] = (bf16)p3;
            *(bf16x4*)(PsW + ((lr * 128 + n * 32 + lg * 8) ^ sxl)) = o;
        }
        lsum += (r0 + r1) + (r2 + r3);
        __builtin_amdgcn_s_setprio(1);
#pragma unroll
        for (int c = 0; c < 2; c++) {
            bf16x8 pa = *(const bf16x8*)(PsW + ((lr * 128 + c * 64 + lg * 16) ^ sxl));
#pragma unroll
            for (int d = 0; d < 4; d++) {
                int row = d * 16 + lr;
                bf16x8 vb = *(const bf16x8*)(VsB + ((row * 128 + c * 64 + lg * 16) ^ ((row & 7) << 4)));
                acc[d] = mfma16(pa, vb, acc[d]);
            }
        }
        __builtin_amdgcn_s_setprio(0);
        cur ^= 1;
    }
    lsum += __shfl_xor(lsum, 16);
    lsum += __shfl_xor(lsum, 32);
    float lb[4];
#pragma unroll
    for (int j = 0; j < 4; j++) lb[j] = __shfl(lsum, lg * 4 + j);
#pragma unroll
    for (int j = 0; j < 4; j++) {
        float inv = 1.f / lb[j];
#pragma unroll
        for (int d = 0; d < 4; d++)
            CTX[(bS + qbase + lg * 4 + j) * 1024 + h * 64 + d * 16 + lr] = f2b(acc[d][j] * inv);
    }
}

extern "C" void kernel_launch(void* const* d_in, const int* in_sizes, int n_in,
                              void* d_out, int out_size, void* d_ws, size_t ws_size,
                              hipStream_t stream) {
    const float* queries = (const float*)d_in[0];
    const float* keys    = (const float*)d_in[1];
    const float* values  = (const float*)d_in[2];
    const float* Wq = (const float*)d_in[3];
    const float* Wk = (const float*)d_in[4];
    const float* Wv = (const float*)d_in[5];
    const float* Wo = (const float*)d_in[6];
    const int* mask = (const int*)d_in[7];

    float* out = (float*)d_out;                       // [4,1024,1024]
    float* aw  = out + ((size_t)4 << 20);             // [4,1024,1024]

    bf16* wsb = (bf16*)d_ws;
    bf16* WtQ = wsb;                                  // transposed weights (Q,K,V,O)
    bf16* Qa  = wsb + ((size_t)4 << 20);              // bf16 queries; reused as CTX
    bf16* Qw  = wsb + ((size_t)8 << 20);
    bf16* Kw  = wsb + ((size_t)12 << 20);
    bf16* VtG = wsb + ((size_t)16 << 20);             // [1024][4096] V transposed
    bf16* Ka  = (bf16*)aw;                            // scratch in aw (dead before oa)
    bf16* Va  = (bf16*)aw + ((size_t)4 << 20);
    bf16* CTX = Qa;

    prep<<<dim3(7168), 256, 0, stream>>>(queries, keys, values, Wq, Wk, Wv, Wo,
                                         Qa, Ka, Va, WtQ);
    gemm8<<<dim3(16, 4, 3), 512, 0, stream>>>(Qa, Ka, Va, WtQ, Qw, Kw, VtG);
    flash_k<<<dim3(1024), 256, 0, stream>>>(Qw, Kw, VtG, CTX, mask);
    gemm_oa<<<dim3(32, 8, 2), 256, 0, stream>>>(CTX, WtQ + ((size_t)3 << 20), out,
                                                Qw, Kw, aw, mask);
}

// Round 13
// 109.596 us; speedup vs baseline: 2.0324x; 1.0646x over previous
//
#include <hip/hip_runtime.h>
#include <hip/hip_bf16.h>

typedef __bf16 bf16;
typedef __attribute__((ext_vector_type(8))) __bf16 bf16x8;
typedef __attribute__((ext_vector_type(4))) __bf16 bf16x4;
typedef __attribute__((ext_vector_type(4))) float f32x4;

#define NEGV (-1e18f)
#define LOG2E 1.4426950408889634f

__device__ __forceinline__ bf16 f2b(float f) {
    unsigned u = __builtin_bit_cast(unsigned, f);
    u += 0x7fffu + ((u >> 16) & 1u);
    unsigned short h = (unsigned short)(u >> 16);
    return __builtin_bit_cast(bf16, h);
}

__device__ __forceinline__ f32x4 mfma16(bf16x8 a, bf16x8 b, f32x4 c) {
    return __builtin_amdgcn_mfma_f32_16x16x32_bf16(a, b, c, 0, 0, 0);
}

__device__ __forceinline__ void gl16(const void* g, void* l) {
    __builtin_amdgcn_global_load_lds((const __attribute__((address_space(1))) void*)g,
                                     (__attribute__((address_space(3))) void*)l, 16, 0, 0);
}

// ---------------------------------------------------------------------------
// prep: merged weight-transpose+convert (blocks >= 6144) and activation
// f32->bf16 convert (blocks < 6144). One launch. HBM-bound at ~6.5 TB/s.
// ---------------------------------------------------------------------------
__global__ __launch_bounds__(256) void prep(const float* __restrict__ Qf,
                                            const float* __restrict__ Kf,
                                            const float* __restrict__ Vf,
                                            const float* __restrict__ W0,
                                            const float* __restrict__ W1,
                                            const float* __restrict__ W2,
                                            const float* __restrict__ W3,
                                            bf16* __restrict__ Qa,
                                            bf16* __restrict__ Ka,
                                            bf16* __restrict__ Va,
                                            bf16* __restrict__ Wout) {
    __shared__ float tile[64][65];
    int bx = blockIdx.x;
    int t = threadIdx.x;
    if (bx < 6144) {
        int z = bx >> 11, x = bx & 2047;
        const float* in = (z == 0) ? Qf : (z == 1) ? Kf : Vf;
        bf16* out = (z == 0) ? Qa : (z == 1) ? Ka : Va;
        size_t i = ((size_t)x * 256 + t) * 8;
        float4 a = *(const float4*)&in[i];
        float4 b = *(const float4*)&in[i + 4];
        bf16x8 o;
        o[0] = f2b(a.x); o[1] = f2b(a.y); o[2] = f2b(a.z); o[3] = f2b(a.w);
        o[4] = f2b(b.x); o[5] = f2b(b.y); o[6] = f2b(b.z); o[7] = f2b(b.w);
        *(bf16x8*)&out[i] = o;
        return;
    }
    int w = bx - 6144;
    int z = w >> 8;
    const float* Ws[4] = {W0, W1, W2, W3};
    const float* W = Ws[z];
    bf16* O = Wout + ((size_t)z << 20);
    int k0 = (w & 15) * 64, n0 = ((w >> 4) & 15) * 64;
#pragma unroll
    for (int p = 0; p < 4; p++) {
        int r = (t >> 4) + p * 16, c = (t & 15) * 4;
        float4 v = *(const float4*)&W[(size_t)(k0 + r) * 1024 + n0 + c];
        tile[r][c] = v.x; tile[r][c + 1] = v.y; tile[r][c + 2] = v.z; tile[r][c + 3] = v.w;
    }
    __syncthreads();
#pragma unroll
    for (int p = 0; p < 4; p++) {
        int r = (t >> 4) + p * 16, c = (t & 15) * 4;
        bf16x4 o;
        o[0] = f2b(tile[c][r]); o[1] = f2b(tile[c + 1][r]);
        o[2] = f2b(tile[c + 2][r]); o[3] = f2b(tile[c + 3][r]);
        *(bf16x4*)&O[(size_t)(n0 + r) * 1024 + k0 + c] = o;
    }
}

// ---------------------------------------------------------------------------
// Projection GEMM: gemm_oa structure (128x128, BK=64, single-buffer gl16 both
// sides, pre-swizzled source) at grid (32,8,3) = 768 blocks = 3 blocks/CU
// all-resident — implicit cross-block overlap (m114) beats the 1-block/CU
// 8-phase at this short K (measured: oa ~730 TF vs gemm8 594 TF).
// z=0: Qw*0.125, z=1: Kw, z=2: VtG (C^T out [1024][4096]).
// ---------------------------------------------------------------------------
__global__ __launch_bounds__(256, 3) void gemm_proj3(const bf16* __restrict__ Qa,
                                                     const bf16* __restrict__ Ka,
                                                     const bf16* __restrict__ Va,
                                                     const bf16* __restrict__ WtQ,
                                                     bf16* __restrict__ Qw,
                                                     bf16* __restrict__ Kw,
                                                     bf16* __restrict__ VtG) {
    __shared__ bf16 As[128 * 64];
    __shared__ bf16 Bs[128 * 64];
    char* AsB = (char*)As;
    char* BsB = (char*)Bs;
    int t = threadIdx.x;
    int z = blockIdx.z;
    const bf16* A = (z == 0) ? Qa : (z == 1) ? Ka : Va;
    const bf16* Bt = WtQ + ((size_t)z << 20);
    int m0 = blockIdx.x * 128, n0 = blockIdx.y * 128;
    int wid = t >> 6, lane = t & 63;
    int wr = wid >> 1, wc = wid & 1, lr = lane & 15, lg = lane >> 4;
    f32x4 zero = {0.f, 0.f, 0.f, 0.f};
    f32x4 acc[4][4];
#pragma unroll
    for (int m = 0; m < 4; m++)
#pragma unroll
        for (int n = 0; n < 4; n++) acc[m][n] = zero;

    for (int k0 = 0; k0 < 1024; k0 += 64) {
        __syncthreads();
#pragma unroll
        for (int i = 0; i < 4; i++) {
            int c = wid * 256 + i * 64 + lane;
            int row = c >> 3, q = (c & 7) ^ (row & 7);
            gl16(&A[(size_t)(m0 + row) * 1024 + k0 + q * 8], (void*)&As[c * 8]);
            gl16(&Bt[(size_t)(n0 + row) * 1024 + k0 + q * 8], (void*)&Bs[c * 8]);
        }
        __syncthreads();
#pragma unroll
        for (int kk = 0; kk < 2; kk++) {
            bf16x8 af[4], bfr[4];
#pragma unroll
            for (int m = 0; m < 4; m++) {
                int row = wr * 64 + m * 16 + lr;
                af[m] = *(const bf16x8*)(AsB + ((row * 128 + kk * 64 + lg * 16) ^ ((row & 7) << 4)));
            }
#pragma unroll
            for (int n = 0; n < 4; n++) {
                int row = wc * 64 + n * 16 + lr;
                bfr[n] = *(const bf16x8*)(BsB + ((row * 128 + kk * 64 + lg * 16) ^ ((row & 7) << 4)));
            }
#pragma unroll
            for (int m = 0; m < 4; m++)
#pragma unroll
                for (int n = 0; n < 4; n++) acc[m][n] = mfma16(af[m], bfr[n], acc[m][n]);
        }
    }
#pragma unroll
    for (int n = 0; n < 4; n++) {
        int colg = n0 + wc * 64 + n * 16 + lr;
#pragma unroll
        for (int m = 0; m < 4; m++) {
            int rowg = m0 + wr * 64 + m * 16 + lg * 4;
            if (z == 2) {
                bf16x4 o;
#pragma unroll
                for (int j = 0; j < 4; j++) o[j] = f2b(acc[m][n][j]);
                *(bf16x4*)&VtG[(size_t)colg * 4096 + rowg] = o;
            } else {
                bf16* C = (z == 0) ? Qw : Kw;
                float sc = (z == 0) ? 0.125f : 1.0f;
#pragma unroll
                for (int j = 0; j < 4; j++)
                    C[(size_t)(rowg + j) * 1024 + colg] = f2b(acc[m][n][j] * sc);
            }
        }
    }
}

// ---------------------------------------------------------------------------
// Merged output + attention_weights GEMM (proven single-buffer, BK=64).
// ---------------------------------------------------------------------------
__global__ __launch_bounds__(256, 3) void gemm_oa(const bf16* __restrict__ CTX,
                                                  const bf16* __restrict__ WtO,
                                                  float* __restrict__ out,
                                                  const bf16* __restrict__ Qw,
                                                  const bf16* __restrict__ Kw,
                                                  float* __restrict__ aw,
                                                  const int* __restrict__ maskp) {
    __shared__ bf16 As[128 * 64];
    __shared__ bf16 Bs[128 * 64];
    char* AsB = (char*)As;
    char* BsB = (char*)Bs;
    int t = threadIdx.x;
    int z = blockIdx.z;
    int bx = blockIdx.x;
    int m0, n0 = blockIdx.y * 128;
    const bf16* A;
    const bf16* Bt;
    float* C;
    const int* mask = nullptr;
    if (z == 0) {
        m0 = bx * 128;
        A = CTX; Bt = WtO; C = out;
    } else {
        int b = bx >> 3;
        m0 = (bx & 7) * 128;
        A = Qw + ((size_t)b << 20); Bt = Kw + ((size_t)b << 20);
        C = aw + ((size_t)b << 20); mask = maskp + b * 1024;
    }
    int wid = t >> 6, lane = t & 63;
    int wr = wid >> 1, wc = wid & 1, lr = lane & 15, lg = lane >> 4;
    f32x4 zero = {0.f, 0.f, 0.f, 0.f};
    f32x4 acc[4][4];
#pragma unroll
    for (int m = 0; m < 4; m++)
#pragma unroll
        for (int n = 0; n < 4; n++) acc[m][n] = zero;

    for (int k0 = 0; k0 < 1024; k0 += 64) {
        __syncthreads();
#pragma unroll
        for (int i = 0; i < 4; i++) {
            int c = wid * 256 + i * 64 + lane;
            int row = c >> 3, q = (c & 7) ^ (row & 7);
            gl16(&A[(size_t)(m0 + row) * 1024 + k0 + q * 8], (void*)&As[c * 8]);
            gl16(&Bt[(size_t)(n0 + row) * 1024 + k0 + q * 8], (void*)&Bs[c * 8]);
        }
        __syncthreads();
#pragma unroll
        for (int kk = 0; kk < 2; kk++) {
            bf16x8 af[4], bfr[4];
#pragma unroll
            for (int m = 0; m < 4; m++) {
                int row = wr * 64 + m * 16 + lr;
                af[m] = *(const bf16x8*)(AsB + ((row * 128 + kk * 64 + lg * 16) ^ ((row & 7) << 4)));
            }
#pragma unroll
            for (int n = 0; n < 4; n++) {
                int row = wc * 64 + n * 16 + lr;
                bfr[n] = *(const bf16x8*)(BsB + ((row * 128 + kk * 64 + lg * 16) ^ ((row & 7) << 4)));
            }
#pragma unroll
            for (int m = 0; m < 4; m++)
#pragma unroll
                for (int n = 0; n < 4; n++) acc[m][n] = mfma16(af[m], bfr[n], acc[m][n]);
        }
    }
#pragma unroll
    for (int n = 0; n < 4; n++) {
        int colg = n0 + wc * 64 + n * 16 + lr;
        int mk = (z == 1) ? mask[colg] : 0;
#pragma unroll
        for (int m = 0; m < 4; m++) {
            int rowg = m0 + wr * 64 + m * 16 + lg * 4;
#pragma unroll
            for (int j = 0; j < 4; j++) {
                float v = acc[m][n][j];
                size_t idx = (size_t)(rowg + j) * 1024 + colg;
                if (z == 0) C[idx] = v;
                else C[idx] = mk ? NEGV : v * (1.f / 16.f);
            }
        }
    }
}

// ---------------------------------------------------------------------------
// Flash attention v6: no-max unnormalized softmax, per-lane partial sums,
// K dbuf, XCD-locality swizzle.
// ---------------------------------------------------------------------------
__global__ __launch_bounds__(256, 4) void flash_k(const bf16* __restrict__ Q,
                                                  const bf16* __restrict__ K,
                                                  const bf16* __restrict__ VT,
                                                  bf16* __restrict__ CTX,
                                                  const int* __restrict__ maskp) {
    __shared__ bf16 Ks[2][64 * 64];
    __shared__ bf16 Vs[64 * 64];
    __shared__ bf16 Ps[4][16 * 64];
    __shared__ float biasS[1024];
    int raw = blockIdx.x;
    int idx = raw >> 3;
    int bh = (raw & 7) * 8 + (idx & 7);
    int qt = idx >> 3;
    int b = bh >> 4, h = bh & 15;
    int t = threadIdx.x, wid = t >> 6, lane = t & 63;
    int lr = lane & 15, lg = lane >> 4;
    int qbase = qt * 64 + wid * 16;
    const size_t bS = (size_t)b * 1024;
    char* KsB = (char*)Ks;
    char* VsB = (char*)Vs;
    char* PsW = (char*)&Ps[wid][0];
    const int sxl = (lr & 7) << 4;

    {
        int4 mv = *(const int4*)&maskp[b * 1024 + t * 4];
        float4 bv;
        const float NB = NEGV * LOG2E;
        bv.x = mv.x ? NB : 0.f; bv.y = mv.y ? NB : 0.f;
        bv.z = mv.z ? NB : 0.f; bv.w = mv.w ? NB : 0.f;
        *(float4*)&biasS[t * 4] = bv;
    }

    bf16x8 qf[2];
#pragma unroll
    for (int c = 0; c < 2; c++)
        qf[c] = *(const bf16x8*)&Q[(bS + qbase + lr) * 1024 + h * 64 + c * 32 + lg * 8];

    f32x4 zero = {0.f, 0.f, 0.f, 0.f};
    f32x4 acc[4];
#pragma unroll
    for (int d = 0; d < 4; d++) acc[d] = zero;
    float lsum = 0.f;

    const bf16* Kbase = K + bS * 1024 + h * 64;
    const bf16* Vbase = VT + (size_t)(h * 64) * 4096 + bS;

    int c0 = t, c1 = t + 256;
    int kr0 = c0 >> 3, kq0 = c0 & 7, kr1 = c1 >> 3, kq1 = c1 & 7;
    const int kw0 = (kr0 * 128 + kq0 * 16) ^ ((kr0 & 7) << 4);
    const int kw1 = (kr1 * 128 + kq1 * 16) ^ ((kr1 & 7) << 4);

    {
        bf16x8 t0 = *(const bf16x8*)&Kbase[(size_t)kr0 * 1024 + kq0 * 8];
        bf16x8 t1 = *(const bf16x8*)&Kbase[(size_t)kr1 * 1024 + kq1 * 8];
        *(bf16x8*)(KsB + kw0) = t0;
        *(bf16x8*)(KsB + kw1) = t1;
    }
    bf16x8 kg[2], vg[2];
    vg[0] = *(const bf16x8*)&Vbase[(size_t)kr0 * 4096 + kq0 * 8];
    vg[1] = *(const bf16x8*)&Vbase[(size_t)kr1 * 4096 + kq1 * 8];
    kg[0] = *(const bf16x8*)&Kbase[(size_t)(64 + kr0) * 1024 + kq0 * 8];
    kg[1] = *(const bf16x8*)&Kbase[(size_t)(64 + kr1) * 1024 + kq1 * 8];

    int cur = 0;
    for (int kt = 0; kt < 16; kt++) {
        __syncthreads();
        *(bf16x8*)(VsB + kw0) = vg[0];
        *(bf16x8*)(VsB + kw1) = vg[1];
        if (kt < 15) {
            *(bf16x8*)(KsB + (cur ^ 1) * 8192 + kw0) = kg[0];
            *(bf16x8*)(KsB + (cur ^ 1) * 8192 + kw1) = kg[1];
            size_t ko = (size_t)(kt + 1) * 64;
            vg[0] = *(const bf16x8*)&Vbase[(size_t)kr0 * 4096 + ko + kq0 * 8];
            vg[1] = *(const bf16x8*)&Vbase[(size_t)kr1 * 4096 + ko + kq1 * 8];
            if (kt < 14) {
                kg[0] = *(const bf16x8*)&Kbase[(ko + 64 + kr0) * 1024 + kq0 * 8];
                kg[1] = *(const bf16x8*)&Kbase[(ko + 64 + kr1) * 1024 + kq1 * 8];
            }
        }
        f32x4 s[4];
        __builtin_amdgcn_s_setprio(1);
#pragma unroll
        for (int n = 0; n < 4; n++) {
            int row = n * 16 + lr;
            bf16x8 kf0 = *(const bf16x8*)(KsB + cur * 8192 + ((row * 128 + lg * 16) ^ sxl));
            bf16x8 kf1 = *(const bf16x8*)(KsB + cur * 8192 + ((row * 128 + 64 + lg * 16) ^ sxl));
            f32x4 zz = zero;
            zz = mfma16(kf0, qf[0], zz);
            zz = mfma16(kf1, qf[1], zz);
            s[n] = zz;
        }
        __builtin_amdgcn_s_setprio(0);
        __syncthreads();
        float r0 = 0.f, r1 = 0.f, r2 = 0.f, r3 = 0.f;
#pragma unroll
        for (int n = 0; n < 4; n++) {
            float4 bv = *(const float4*)&biasS[kt * 64 + n * 16 + lg * 4];
            float p0 = __builtin_exp2f(__builtin_fmaf(s[n][0], LOG2E, bv.x));
            float p1 = __builtin_exp2f(__builtin_fmaf(s[n][1], LOG2E, bv.y));
            float p2 = __builtin_exp2f(__builtin_fmaf(s[n][2], LOG2E, bv.z));
            float p3 = __builtin_exp2f(__builtin_fmaf(s[n][3], LOG2E, bv.w));
            r0 += p0; r1 += p1; r2 += p2; r3 += p3;
            bf16x4 o;
            o[0] = (bf16)p0; o[1] = (bf16)p1; o[2] = (bf16)p2; o[3] = (bf16)p3;
            *(bf16x4*)(PsW + ((lr * 128 + n * 32 + lg * 8) ^ sxl)) = o;
        }
        lsum += (r0 + r1) + (r2 + r3);
        __builtin_amdgcn_s_setprio(1);
#pragma unroll
        for (int c = 0; c < 2; c++) {
            bf16x8 pa = *(const bf16x8*)(PsW + ((lr * 128 + c * 64 + lg * 16) ^ sxl));
#pragma unroll
            for (int d = 0; d < 4; d++) {
                int row = d * 16 + lr;
                bf16x8 vb = *(const bf16x8*)(VsB + ((row * 128 + c * 64 + lg * 16) ^ ((row & 7) << 4)));
                acc[d] = mfma16(pa, vb, acc[d]);
            }
        }
        __builtin_amdgcn_s_setprio(0);
        cur ^= 1;
    }
    lsum += __shfl_xor(lsum, 16);
    lsum += __shfl_xor(lsum, 32);
    float lb[4];
#pragma unroll
    for (int j = 0; j < 4; j++) lb[j] = __shfl(lsum, lg * 4 + j);
#pragma unroll
    for (int j = 0; j < 4; j++) {
        float inv = 1.f / lb[j];
#pragma unroll
        for (int d = 0; d < 4; d++)
            CTX[(bS + qbase + lg * 4 + j) * 1024 + h * 64 + d * 16 + lr] = f2b(acc[d][j] * inv);
    }
}

extern "C" void kernel_launch(void* const* d_in, const int* in_sizes, int n_in,
                              void* d_out, int out_size, void* d_ws, size_t ws_size,
                              hipStream_t stream) {
    const float* queries = (const float*)d_in[0];
    const float* keys    = (const float*)d_in[1];
    const float* values  = (const float*)d_in[2];
    const float* Wq = (const float*)d_in[3];
    const float* Wk = (const float*)d_in[4];
    const float* Wv = (const float*)d_in[5];
    const float* Wo = (const float*)d_in[6];
    const int* mask = (const int*)d_in[7];

    float* out = (float*)d_out;                       // [4,1024,1024]
    float* aw  = out + ((size_t)4 << 20);             // [4,1024,1024]

    bf16* wsb = (bf16*)d_ws;
    bf16* WtQ = wsb;                                  // transposed weights (Q,K,V,O)
    bf16* Qa  = wsb + ((size_t)4 << 20);              // bf16 queries; reused as CTX
    bf16* Qw  = wsb + ((size_t)8 << 20);
    bf16* Kw  = wsb + ((size_t)12 << 20);
    bf16* VtG = wsb + ((size_t)16 << 20);             // [1024][4096] V transposed
    bf16* Ka  = (bf16*)aw;                            // scratch in aw (dead before oa)
    bf16* Va  = (bf16*)aw + ((size_t)4 << 20);
    bf16* CTX = Qa;

    prep<<<dim3(7168), 256, 0, stream>>>(queries, keys, values, Wq, Wk, Wv, Wo,
                                         Qa, Ka, Va, WtQ);
    gemm_proj3<<<dim3(32, 8, 3), 256, 0, stream>>>(Qa, Ka, Va, WtQ, Qw, Kw, VtG);
    flash_k<<<dim3(1024), 256, 0, stream>>>(Qw, Kw, VtG, CTX, mask);
    gemm_oa<<<dim3(32, 8, 2), 256, 0, stream>>>(CTX, WtQ + ((size_t)3 << 20), out,
                                                Qw, Kw, aw, mask);
}